// Round 13
// baseline (389.100 us; speedup 1.0000x reference)
//
#include <hip/hip_runtime.h>
#include <hip/hip_bf16.h>

#define N_NODES 50000
#define N_EDGES 800000
#define N_GRAPHS 128
#define IN_CH 16
#define HIDDEN 64
#define OUT_CH 2

// ---- bucket CSR params ----
#define BSHIFT 7
#define BNODES 128
#define NB ((N_NODES + BNODES - 1) / BNODES)     // 391 buckets
#define BCAP 3072                                // per-bucket csr capacity (mean 2046, sd ~45)
#define ECHUNK 4096
#define EB ((N_EDGES + ECHUNK - 1) / ECHUNK)     // 196 edge blocks
#define MAXK 12                                  // BCAP/256
#define EPT 16                                   // edges per thread in scatter (4096/256)
#define WT1_LD 18                                // W1^T stride: 2-way banks (free)
#define AGG_LD 72                                // bf16 LDS stride for MFMA frags
#define W2T_ENT (HIDDEN * AGG_LD)                // 4608 ushorts prepped W2^T

typedef __attribute__((ext_vector_type(8))) short bf16x8;
typedef __attribute__((ext_vector_type(4))) float f32x4;

__device__ __forceinline__ float bf2f(unsigned short u) {
    return __uint_as_float(((unsigned)u) << 16);
}
__device__ __forceinline__ unsigned short f2bf(float f) {
    __hip_bfloat16 h = __float2bfloat16(f);
    return *reinterpret_cast<unsigned short*>(&h);
}

// ---------------- S1: in-block bucket sort (ZERO global atomics, no init needed) ----------------

// Each block sorts its 4096 edges by bucket into its own pairs region
// [base, base+nE), publishing bh[b*EB+blk]=count and bh2[b*EB+blk]=global start.
// Block 0 additionally preps W2^T bf16 for fused_l2.
__global__ void bucket_scatter_kernel(const int* __restrict__ src, const int* __restrict__ dst,
                                      int* __restrict__ bh, int* __restrict__ bh2,
                                      int* __restrict__ pairs,
                                      const float* __restrict__ W2, unsigned short* __restrict__ w2t) {
    __shared__ int lh[NB];      // counts, then reused as cursors
    __shared__ int lstart[NB];  // exclusive prefix within block
    __shared__ int spair[256];  // scan temp
    int t = threadIdx.x;
    if (blockIdx.x == 0) {
        for (int i = t; i < HIDDEN * HIDDEN; i += 256) {
            int k = i >> 6, c = i & 63;
            w2t[c * AGG_LD + k] = f2bf(W2[i]);
        }
    }
    for (int i = t; i < NB; i += 256) lh[i] = 0;
    __syncthreads();

    int base = blockIdx.x * ECHUNK;
    int nE = N_EDGES - base;
    if (nE > ECHUNK) nE = ECHUNK;

    int ed[EPT], es[EPT];
#pragma unroll
    for (int k = 0; k < EPT; k++) {
        int i = k * 256 + t;
        if (i < nE) {
            ed[k] = dst[base + i];
            es[k] = src[base + i];
        } else {
            ed[k] = -1;
            es[k] = 0;
        }
    }
#pragma unroll
    for (int k = 0; k < EPT; k++)
        if ((unsigned)ed[k] < N_NODES) atomicAdd(&lh[ed[k] >> BSHIFT], 1);
    __syncthreads();

    // exclusive prefix over lh[0..NB): 2 entries/thread + 256-wide Hillis-Steele
    int a0 = (2 * t < NB) ? lh[2 * t] : 0;
    int a1 = (2 * t + 1 < NB) ? lh[2 * t + 1] : 0;
    spair[t] = a0 + a1;
    __syncthreads();
    for (int off = 1; off < 256; off <<= 1) {
        int u = (t >= off) ? spair[t - off] : 0;
        __syncthreads();
        spair[t] += u;
        __syncthreads();
    }
    int ex = spair[t] - (a0 + a1);
    if (2 * t < NB) lstart[2 * t] = ex;
    if (2 * t + 1 < NB) lstart[2 * t + 1] = ex + a0;
    __syncthreads();

    // publish tables, reset cursors
    for (int i = t; i < NB; i += 256) {
        bh[i * EB + blockIdx.x] = lh[i];
        bh2[i * EB + blockIdx.x] = base + lstart[i];
        lh[i] = 0;
    }
    __syncthreads();

#pragma unroll
    for (int k = 0; k < EPT; k++) {
        if ((unsigned)ed[k] < N_NODES) {
            int b = ed[k] >> BSHIFT;
            int r = atomicAdd(&lh[b], 1);
            pairs[base + lstart[b] + r] = (es[k] << BSHIFT) | (ed[k] & (BNODES - 1));
        }
    }
}

// ---------------- S2: per-bucket exact CSR (+dinv, +x', + zero sums/cntg/done) ----------------

__global__ void bucket_csr_kernel(const int* __restrict__ pairs, const int* __restrict__ bh,
                                  const int* __restrict__ bh2,
                                  int* __restrict__ csr, int* __restrict__ rowptr,
                                  int* __restrict__ cnt_node, float* __restrict__ dinv,
                                  const float* __restrict__ x, float* __restrict__ xs,
                                  float* __restrict__ sums, float* __restrict__ cntg,
                                  int* __restrict__ done) {
    __shared__ int segaddr[EB];
    __shared__ int pref[EB];       // inclusive prefix of segment counts
    __shared__ int ptmp[256];
    __shared__ int lcnt[BNODES];
    __shared__ int lsc[BNODES];
    __shared__ int lrow[BNODES];
    __shared__ float sdv[BNODES];
    int b = blockIdx.x;
    int t = threadIdx.x;

    if (b == 0) {   // zero everything the later kernels accumulate into
        for (int i = t; i < N_GRAPHS * HIDDEN; i += 256) sums[i] = 0.0f;
        if (t < N_GRAPHS) cntg[t] = 0.0f;
        if (t == 0) *done = 0;
    }

    int cntv = (t < EB) ? bh[b * EB + t] : 0;
    if (t < EB) segaddr[t] = bh2[b * EB + t];
    if (t < BNODES) lcnt[t] = 0;
    ptmp[t] = cntv;
    __syncthreads();
    for (int off = 1; off < 256; off <<= 1) {
        int u = (t >= off) ? ptmp[t - off] : 0;
        __syncthreads();
        ptmp[t] += u;
        __syncthreads();
    }
    if (t < EB) pref[t] = ptmp[t];
    __syncthreads();
    int K = pref[EB - 1];
    if (K > BCAP) K = BCAP;   // safety cap (matches csr region capacity)

    int myp[MAXK], myr[MAXK];
#pragma unroll
    for (int k = 0; k < MAXK; k++) {
        int i = k * 256 + t;
        myp[k] = -1;
        if (i < K) {
            int lo = 0, hi = EB - 1;          // smallest seg with pref[seg] > i
            while (lo < hi) {
                int mid = (lo + hi) >> 1;
                if (pref[mid] > i) hi = mid; else lo = mid + 1;
            }
            int excl = (lo > 0) ? pref[lo - 1] : 0;
            int p = pairs[segaddr[lo] + (i - excl)];
            myp[k] = p;
            myr[k] = atomicAdd(&lcnt[p & (BNODES - 1)], 1);
        }
    }
    __syncthreads();
    if (t < BNODES) lsc[t] = lcnt[t];
    __syncthreads();
    for (int off = 1; off < BNODES; off <<= 1) {
        int u = (t >= off && t < BNODES) ? lsc[t - off] : 0;
        __syncthreads();
        if (t < BNODES) lsc[t] += u;
        __syncthreads();
    }
    int bstart = b * BCAP;
    if (t < BNODES) {
        int ex = lsc[t] - lcnt[t];
        lrow[t] = ex;
        float dv = rsqrtf((float)(lcnt[t] + 1));  // +1 self-loop
        sdv[t] = dv;
        int n = b * BNODES + t;
        if (n < N_NODES) {
            rowptr[n] = bstart + ex;
            cnt_node[n] = lcnt[t];
            dinv[n] = dv;
        }
    }
    __syncthreads();
#pragma unroll
    for (int k = 0; k < MAXK; k++) {
        if (myp[k] >= 0)
            csr[bstart + lrow[myp[k] & (BNODES - 1)] + myr[k]] = myp[k] >> BSHIFT;
    }
    // prep x' = dinv * x for this bucket's 128 nodes
    for (int i = t; i < BNODES * IN_CH; i += 256) {
        int nl = i >> 4;
        int n = b * BNODES + nl;
        if (n < N_NODES) xs[n * IN_CH + (i & 15)] = sdv[nl] * x[n * IN_CH + (i & 15)];
    }
}

// ---------------- fused layer 1: aggregate(x') -> LDS -> linear+relu -> h1' (bf16, pre-scaled) ----------------

__global__ void fused_l1_kernel(const float* __restrict__ xs, const int* __restrict__ csr_src,
                                const int* __restrict__ rowptr, const int* __restrict__ cnt,
                                const float* __restrict__ dinv, const float* __restrict__ W,
                                const float* __restrict__ b, __hip_bfloat16* __restrict__ h) {
    __shared__ float sWT[HIDDEN * WT1_LD];   // 4.6 KB
    __shared__ float sx[16 * IN_CH];         // 1 KB
    int t = threadIdx.x;
    for (int i = t; i < IN_CH * HIDDEN; i += 256) {
        int k = i >> 6, c = i & 63;
        sWT[c * WT1_LD + k] = W[i];
    }

    int n0 = blockIdx.x * 16;
    int w = t >> 6;
    int lane = t & 63;
    int e16 = lane >> 2;          // edge slot 0..15
    int cc = (lane & 3) * 4;      // channel quad

    int lens[4], starts[4];
#pragma unroll
    for (int q = 0; q < 4; q++) {
        int n = n0 + w * 4 + q;
        lens[q] = cnt[n];
        starts[q] = rowptr[n];
    }

    for (int q = 0; q < 4; q++) {
        int row = w * 4 + q;
        int n = n0 + row;
        int len = lens[q];
        int start = starts[q];
        int last = len - 1;
        int iters = (len + 31) >> 5;   // wave-uniform, 32 edges per iter
        float4 acc = make_float4(0.f, 0.f, 0.f, 0.f);
        for (int m = 0; m < iters; m++) {
            int base = m * 32 + e16;
#pragma unroll
            for (int k = 0; k < 2; k++) {
                int j = base + 16 * k;
                int jj = j <= last ? j : last;
                float msk = j <= last ? 1.0f : 0.0f;
                int s = csr_src[start + jj];
                float4 xv = *(const float4*)&xs[s * IN_CH + cc];
                acc.x += msk * xv.x; acc.y += msk * xv.y;
                acc.z += msk * xv.z; acc.w += msk * xv.w;
            }
        }
#pragma unroll
        for (int m = 4; m <= 32; m <<= 1) {
            acc.x += __shfl_xor(acc.x, m, 64);
            acc.y += __shfl_xor(acc.y, m, 64);
            acc.z += __shfl_xor(acc.z, m, 64);
            acc.w += __shfl_xor(acc.w, m, 64);
        }
        if (lane < 4) {
            float dn = dinv[n];
            float4 xsv = *(const float4*)&xs[n * IN_CH + cc];
            float4 v;
            v.x = dn * (acc.x + xsv.x);
            v.y = dn * (acc.y + xsv.y);
            v.z = dn * (acc.z + xsv.z);
            v.w = dn * (acc.w + xsv.w);
            *(float4*)&sx[row * IN_CH + cc] = v;
        }
    }
    __syncthreads();

    int r = w;
    int c = t & 63;
    float bias = b[c];
#pragma unroll
    for (int nb = 0; nb < 4; nb++) {
        int row = nb * 4 + r;
        int n = n0 + row;
        if (n >= N_NODES) continue;
        float acch = bias;
#pragma unroll
        for (int k4 = 0; k4 < IN_CH; k4 += 4) {
            float4 a = *(const float4*)&sx[row * IN_CH + k4];
            float2 w0 = *(const float2*)&sWT[c * WT1_LD + k4];
            float2 w1 = *(const float2*)&sWT[c * WT1_LD + k4 + 2];
            acch += a.x * w0.x + a.y * w0.y + a.z * w1.x + a.w * w1.y;
        }
        float v = acch > 0.0f ? acch : 0.0f;
        h[n * HIDDEN + c] = __float2bfloat16(dinv[n] * v);   // pre-scaled h1'
    }
}

// ---------------- fused layer 2: aggregate(h1') -> MFMA gemm2 -> pool -> (last block) head ----------------

__global__ void fused_l2_kernel(const __hip_bfloat16* __restrict__ h, const int* __restrict__ csr_src,
                                const int* __restrict__ rowptr, const int* __restrict__ cnt,
                                const float* __restrict__ dinv, const unsigned short* __restrict__ w2t,
                                const float* __restrict__ b, const int* __restrict__ batch,
                                float* __restrict__ sums, float* __restrict__ cntg,
                                int* __restrict__ done, const float* __restrict__ Wc,
                                const float* __restrict__ bc, float* __restrict__ out) {
    __shared__ unsigned short sW[W2T_ENT];           // 9.2 KB (prepped, flat copy)
    __shared__ unsigned short sagg[16 * AGG_LD];     // 2.3 KB
    __shared__ int lastFlag;
    int t = threadIdx.x;
    {   // flat uint4 copy of prepped W2^T (conflict-free b128)
        const uint4* wp = (const uint4*)w2t;
        uint4* sWv = (uint4*)sW;
#pragma unroll
        for (int i = 0; i < 3; i++) {
            int idx = i * 256 + t;
            if (idx < W2T_ENT / 8) sWv[idx] = wp[idx];
        }
    }

    int n0 = blockIdx.x * 16;
    int w = t >> 6;
    int lane = t & 63;
    int e8 = lane >> 3;          // edge slot 0..7
    int cc8 = (lane & 7) * 8;    // channel octet
    const unsigned short* hu = (const unsigned short*)h;

    int lens[4], starts[4];
#pragma unroll
    for (int q = 0; q < 4; q++) {
        int n = n0 + w * 4 + q;
        lens[q] = cnt[n];
        starts[q] = rowptr[n];
    }

    for (int q = 0; q < 4; q++) {
        int row = w * 4 + q;
        int n = n0 + row;
        int len = lens[q];
        int start = starts[q];
        int last = len - 1;
        int iters = (len + 31) >> 5;   // 32 edges per iter
        float4 alo = make_float4(0.f, 0.f, 0.f, 0.f);
        float4 ahi = make_float4(0.f, 0.f, 0.f, 0.f);
        for (int m = 0; m < iters; m++) {
            int base = m * 32 + e8;
#pragma unroll
            for (int k = 0; k < 4; k++) {
                int j = base + 8 * k;
                int jj = j <= last ? j : last;
                float msk = j <= last ? 1.0f : 0.0f;
                int s = csr_src[start + jj];
                uint4 raw = *(const uint4*)&hu[s * HIDDEN + cc8];
                alo.x += msk * __uint_as_float(raw.x << 16);
                alo.y += msk * __uint_as_float(raw.x & 0xffff0000u);
                alo.z += msk * __uint_as_float(raw.y << 16);
                alo.w += msk * __uint_as_float(raw.y & 0xffff0000u);
                ahi.x += msk * __uint_as_float(raw.z << 16);
                ahi.y += msk * __uint_as_float(raw.z & 0xffff0000u);
                ahi.z += msk * __uint_as_float(raw.w << 16);
                ahi.w += msk * __uint_as_float(raw.w & 0xffff0000u);
            }
        }
#pragma unroll
        for (int m = 8; m <= 32; m <<= 1) {
            alo.x += __shfl_xor(alo.x, m, 64);
            alo.y += __shfl_xor(alo.y, m, 64);
            alo.z += __shfl_xor(alo.z, m, 64);
            alo.w += __shfl_xor(alo.w, m, 64);
            ahi.x += __shfl_xor(ahi.x, m, 64);
            ahi.y += __shfl_xor(ahi.y, m, 64);
            ahi.z += __shfl_xor(ahi.z, m, 64);
            ahi.w += __shfl_xor(ahi.w, m, 64);
        }
        if (lane < 8) {
            uint4 sv = *(const uint4*)&hu[n * HIDDEN + cc8];
            float dn = dinv[n];
            ushort4 o0, o1;
            o0.x = f2bf(dn * (alo.x + __uint_as_float(sv.x << 16)));
            o0.y = f2bf(dn * (alo.y + __uint_as_float(sv.x & 0xffff0000u)));
            o0.z = f2bf(dn * (alo.z + __uint_as_float(sv.y << 16)));
            o0.w = f2bf(dn * (alo.w + __uint_as_float(sv.y & 0xffff0000u)));
            o1.x = f2bf(dn * (ahi.x + __uint_as_float(sv.z << 16)));
            o1.y = f2bf(dn * (ahi.y + __uint_as_float(sv.z & 0xffff0000u)));
            o1.z = f2bf(dn * (ahi.z + __uint_as_float(sv.w << 16)));
            o1.w = f2bf(dn * (ahi.w + __uint_as_float(sv.w & 0xffff0000u)));
            *(ushort4*)&sagg[row * AGG_LD + cc8] = o0;
            *(ushort4*)&sagg[row * AGG_LD + cc8 + 4] = o1;
        }
    }
    __syncthreads();

    // Phase B: MFMA. Wave w computes all 16 nodes x channels [16w, 16w+16).
    int quad = lane >> 4;
    int col = lane & 15;
    int cch = w * 16 + col;
    bf16x8 a0 = *(const bf16x8*)&sagg[col * AGG_LD + quad * 8];
    bf16x8 a1 = *(const bf16x8*)&sagg[col * AGG_LD + 32 + quad * 8];
    bf16x8 b0 = *(const bf16x8*)&sW[cch * AGG_LD + quad * 8];
    bf16x8 b1 = *(const bf16x8*)&sW[cch * AGG_LD + 32 + quad * 8];
    f32x4 d = {0.f, 0.f, 0.f, 0.f};
    d = __builtin_amdgcn_mfma_f32_16x16x32_bf16(a0, b0, d, 0, 0, 0);
    d = __builtin_amdgcn_mfma_f32_16x16x32_bf16(a1, b1, d, 0, 0, 0);
    float bias = b[cch];
    float v[4];
#pragma unroll
    for (int r = 0; r < 4; r++) {
        float z = d[r] + bias;
        v[r] = z > 0.0f ? z : 0.0f;
    }

    // Phase C: pool from registers (batch sorted -> tile usually one graph)
    int glo = batch[n0];
    int ghi = batch[n0 + 15];
    if (glo == ghi) {
        float s4 = (v[0] + v[1]) + (v[2] + v[3]);
        s4 += __shfl_xor(s4, 16, 64);
        s4 += __shfl_xor(s4, 32, 64);
        if (quad == 0) atomicAdd(&sums[glo * HIDDEN + cch], s4);
        if (t == 0) atomicAdd(&cntg[glo], 16.0f);
    } else {
#pragma unroll
        for (int r = 0; r < 4; r++) {
            int g = batch[n0 + quad * 4 + r];
            if ((unsigned)g < N_GRAPHS) atomicAdd(&sums[g * HIDDEN + cch], v[r]);
        }
        if (w == 0 && col == 0) {
#pragma unroll
            for (int r = 0; r < 4; r++) {
                int g = batch[n0 + quad * 4 + r];
                if ((unsigned)g < N_GRAPHS) atomicAdd(&cntg[g], 1.0f);
            }
        }
    }

    // Phase D: last block computes the head (sums/cntg L2-coherent via atomics).
    __threadfence();
    __syncthreads();
    if (t == 0) lastFlag = (atomicAdd(done, 1) == (int)gridDim.x - 1) ? 1 : 0;
    __syncthreads();
    if (lastFlag) {
        for (int i = t; i < N_GRAPHS * OUT_CH; i += 256) {
            int g = i >> 1;
            int o = i & 1;
            float cg = __hip_atomic_load(&cntg[g], __ATOMIC_RELAXED, __HIP_MEMORY_SCOPE_AGENT);
            float inv = 1.0f / fmaxf(cg, 1.0f);
            float acc = bc[o];
#pragma unroll
            for (int k = 0; k < HIDDEN; k++) {
                float sv = __hip_atomic_load(&sums[g * HIDDEN + k], __ATOMIC_RELAXED,
                                             __HIP_MEMORY_SCOPE_AGENT);
                acc += sv * inv * Wc[k * OUT_CH + o];
            }
            out[i] = acc;
        }
    }
}

// ---------------- launch ----------------

extern "C" void kernel_launch(void* const* d_in, const int* in_sizes, int n_in,
                              void* d_out, int out_size, void* d_ws, size_t ws_size,
                              hipStream_t stream) {
    const float* x  = (const float*)d_in[0];
    const int* ei   = (const int*)d_in[1];
    const int* bat  = (const int*)d_in[2];
    const float* W1 = (const float*)d_in[3];
    const float* b1 = (const float*)d_in[4];
    const float* W2 = (const float*)d_in[5];
    const float* b2 = (const float*)d_in[6];
    const float* Wc = (const float*)d_in[7];
    const float* bc = (const float*)d_in[8];
    float* out = (float*)d_out;

    const int* src = ei;
    const int* dst = ei + N_EDGES;

    char* ws = (char*)d_ws;
    size_t off = 0;
    auto carve = [&](size_t nbytes) {
        char* p = ws + off;
        off += (nbytes + 255) & ~(size_t)255;
        return p;
    };
    float* sums     = (float*)carve(N_GRAPHS * HIDDEN * sizeof(float));
    float* cntg     = (float*)carve(N_GRAPHS * sizeof(float));
    int*   done     = (int*)carve(sizeof(int));
    unsigned short* w2t = (unsigned short*)carve(W2T_ENT * sizeof(unsigned short));
    int*   bh       = (int*)carve((size_t)NB * EB * sizeof(int));
    int*   bh2      = (int*)carve((size_t)NB * EB * sizeof(int));
    int*   pairs    = (int*)carve((size_t)EB * ECHUNK * sizeof(int));
    int*   csr      = (int*)carve((size_t)NB * BCAP * sizeof(int));
    int*   rowptr   = (int*)carve(N_NODES * sizeof(int));
    int*   cnt_node = (int*)carve(N_NODES * sizeof(int));
    float* dinv     = (float*)carve(N_NODES * sizeof(float));
    float* xs       = (float*)carve((size_t)N_NODES * IN_CH * sizeof(float));
    __hip_bfloat16* bufA = (__hip_bfloat16*)carve((size_t)N_NODES * HIDDEN * sizeof(__hip_bfloat16));
    (void)ws_size;

    const int node16Blk = (N_NODES + 15) / 16;   // 3125

    bucket_scatter_kernel<<<EB, 256, 0, stream>>>(src, dst, bh, bh2, pairs, W2, w2t);
    bucket_csr_kernel<<<NB, 256, 0, stream>>>(pairs, bh, bh2, csr, rowptr, cnt_node, dinv,
                                              x, xs, sums, cntg, done);
    fused_l1_kernel<<<node16Blk, 256, 0, stream>>>(xs, csr, rowptr, cnt_node, dinv, W1, b1, bufA);
    fused_l2_kernel<<<node16Blk, 256, 0, stream>>>(bufA, csr, rowptr, cnt_node, dinv, w2t, b2,
                                                   bat, sums, cntg, done, Wc, bc, out);
}

// Round 14
// 166.030 us; speedup vs baseline: 2.3436x; 2.3436x over previous
//
#include <hip/hip_runtime.h>
#include <hip/hip_bf16.h>

#define N_NODES 50000
#define N_EDGES 800000
#define N_GRAPHS 128
#define IN_CH 16
#define HIDDEN 64
#define OUT_CH 2

// ---- bucket CSR params ----
#define BSHIFT 7
#define BNODES 128
#define NB ((N_NODES + BNODES - 1) / BNODES)     // 391 buckets
#define BCAP 3072                                // per-bucket csr capacity (mean 2046, sd ~45)
#define ECHUNK 4096
#define EB ((N_EDGES + ECHUNK - 1) / ECHUNK)     // 196 edge blocks
#define MAXK 12                                  // BCAP/256
#define EPT 16                                   // edges per thread in scatter (4096/256)
#define WT1_LD 18                                // W1^T stride: 2-way banks (free)
#define AGG_LD 72                                // bf16 LDS stride for MFMA frags
#define W2T_ENT (HIDDEN * AGG_LD)                // 4608 ushorts prepped W2^T

typedef __attribute__((ext_vector_type(8))) short bf16x8;
typedef __attribute__((ext_vector_type(4))) float f32x4;

__device__ __forceinline__ float bf2f(unsigned short u) {
    return __uint_as_float(((unsigned)u) << 16);
}
__device__ __forceinline__ unsigned short f2bf(float f) {
    __hip_bfloat16 h = __float2bfloat16(f);
    return *reinterpret_cast<unsigned short*>(&h);
}

// ---------------- S1: in-block bucket sort (zero global atomics, no init needed) ----------------

__global__ void bucket_scatter_kernel(const int* __restrict__ src, const int* __restrict__ dst,
                                      int* __restrict__ bh, int* __restrict__ bh2,
                                      int* __restrict__ pairs,
                                      const float* __restrict__ W2, unsigned short* __restrict__ w2t) {
    __shared__ int lh[NB];      // counts, then reused as cursors
    __shared__ int lstart[NB];  // exclusive prefix within block
    __shared__ int spair[256];  // scan temp
    int t = threadIdx.x;
    if (blockIdx.x == 0) {
        for (int i = t; i < HIDDEN * HIDDEN; i += 256) {
            int k = i >> 6, c = i & 63;
            w2t[c * AGG_LD + k] = f2bf(W2[i]);
        }
    }
    for (int i = t; i < NB; i += 256) lh[i] = 0;
    __syncthreads();

    int base = blockIdx.x * ECHUNK;
    int nE = N_EDGES - base;
    if (nE > ECHUNK) nE = ECHUNK;

    int ed[EPT], es[EPT];
#pragma unroll
    for (int k = 0; k < EPT; k++) {
        int i = k * 256 + t;
        if (i < nE) {
            ed[k] = dst[base + i];
            es[k] = src[base + i];
        } else {
            ed[k] = -1;
            es[k] = 0;
        }
    }
#pragma unroll
    for (int k = 0; k < EPT; k++)
        if ((unsigned)ed[k] < N_NODES) atomicAdd(&lh[ed[k] >> BSHIFT], 1);
    __syncthreads();

    // exclusive prefix over lh[0..NB): 2 entries/thread + 256-wide Hillis-Steele
    int a0 = (2 * t < NB) ? lh[2 * t] : 0;
    int a1 = (2 * t + 1 < NB) ? lh[2 * t + 1] : 0;
    spair[t] = a0 + a1;
    __syncthreads();
    for (int off = 1; off < 256; off <<= 1) {
        int u = (t >= off) ? spair[t - off] : 0;
        __syncthreads();
        spair[t] += u;
        __syncthreads();
    }
    int ex = spair[t] - (a0 + a1);
    if (2 * t < NB) lstart[2 * t] = ex;
    if (2 * t + 1 < NB) lstart[2 * t + 1] = ex + a0;
    __syncthreads();

    // publish tables, reset cursors
    for (int i = t; i < NB; i += 256) {
        bh[i * EB + blockIdx.x] = lh[i];
        bh2[i * EB + blockIdx.x] = base + lstart[i];
        lh[i] = 0;
    }
    __syncthreads();

#pragma unroll
    for (int k = 0; k < EPT; k++) {
        if ((unsigned)ed[k] < N_NODES) {
            int b = ed[k] >> BSHIFT;
            int r = atomicAdd(&lh[b], 1);
            pairs[base + lstart[b] + r] = (es[k] << BSHIFT) | (ed[k] & (BNODES - 1));
        }
    }
}

// ---------------- S2: per-bucket exact CSR (+dinv, +x', + zero sums/cntg) ----------------

__global__ void bucket_csr_kernel(const int* __restrict__ pairs, const int* __restrict__ bh,
                                  const int* __restrict__ bh2,
                                  int* __restrict__ csr, int* __restrict__ rowptr,
                                  int* __restrict__ cnt_node, float* __restrict__ dinv,
                                  const float* __restrict__ x, float* __restrict__ xs,
                                  float* __restrict__ sums, float* __restrict__ cntg) {
    __shared__ int segaddr[EB];
    __shared__ int pref[EB];       // inclusive prefix of segment counts
    __shared__ int ptmp[256];
    __shared__ int lcnt[BNODES];
    __shared__ int lsc[BNODES];
    __shared__ int lrow[BNODES];
    __shared__ float sdv[BNODES];
    int b = blockIdx.x;
    int t = threadIdx.x;

    if (b == 0) {   // zero everything the later kernels accumulate into
        for (int i = t; i < N_GRAPHS * HIDDEN; i += 256) sums[i] = 0.0f;
        if (t < N_GRAPHS) cntg[t] = 0.0f;
    }

    int cntv = (t < EB) ? bh[b * EB + t] : 0;
    if (t < EB) segaddr[t] = bh2[b * EB + t];
    if (t < BNODES) lcnt[t] = 0;
    ptmp[t] = cntv;
    __syncthreads();
    for (int off = 1; off < 256; off <<= 1) {
        int u = (t >= off) ? ptmp[t - off] : 0;
        __syncthreads();
        ptmp[t] += u;
        __syncthreads();
    }
    if (t < EB) pref[t] = ptmp[t];
    __syncthreads();
    int K = pref[EB - 1];
    if (K > BCAP) K = BCAP;   // safety cap (matches csr region capacity)

    int myp[MAXK], myr[MAXK];
#pragma unroll
    for (int k = 0; k < MAXK; k++) {
        int i = k * 256 + t;
        myp[k] = -1;
        if (i < K) {
            int lo = 0, hi = EB - 1;          // smallest seg with pref[seg] > i
            while (lo < hi) {
                int mid = (lo + hi) >> 1;
                if (pref[mid] > i) hi = mid; else lo = mid + 1;
            }
            int excl = (lo > 0) ? pref[lo - 1] : 0;
            int p = pairs[segaddr[lo] + (i - excl)];
            myp[k] = p;
            myr[k] = atomicAdd(&lcnt[p & (BNODES - 1)], 1);
        }
    }
    __syncthreads();
    if (t < BNODES) lsc[t] = lcnt[t];
    __syncthreads();
    for (int off = 1; off < BNODES; off <<= 1) {
        int u = (t >= off && t < BNODES) ? lsc[t - off] : 0;
        __syncthreads();
        if (t < BNODES) lsc[t] += u;
        __syncthreads();
    }
    int bstart = b * BCAP;
    if (t < BNODES) {
        int ex = lsc[t] - lcnt[t];
        lrow[t] = ex;
        float dv = rsqrtf((float)(lcnt[t] + 1));  // +1 self-loop
        sdv[t] = dv;
        int n = b * BNODES + t;
        if (n < N_NODES) {
            rowptr[n] = bstart + ex;
            cnt_node[n] = lcnt[t];
            dinv[n] = dv;
        }
    }
    __syncthreads();
#pragma unroll
    for (int k = 0; k < MAXK; k++) {
        if (myp[k] >= 0)
            csr[bstart + lrow[myp[k] & (BNODES - 1)] + myr[k]] = myp[k] >> BSHIFT;
    }
    // prep x' = dinv * x for this bucket's 128 nodes
    for (int i = t; i < BNODES * IN_CH; i += 256) {
        int nl = i >> 4;
        int n = b * BNODES + nl;
        if (n < N_NODES) xs[n * IN_CH + (i & 15)] = sdv[nl] * x[n * IN_CH + (i & 15)];
    }
}

// ---------------- fused layer 1: aggregate(x') -> LDS -> linear+relu -> h1' (bf16, pre-scaled) ----------------

__global__ void fused_l1_kernel(const float* __restrict__ xs, const int* __restrict__ csr_src,
                                const int* __restrict__ rowptr, const int* __restrict__ cnt,
                                const float* __restrict__ dinv, const float* __restrict__ W,
                                const float* __restrict__ b, __hip_bfloat16* __restrict__ h) {
    __shared__ float sWT[HIDDEN * WT1_LD];   // 4.6 KB
    __shared__ float sx[16 * IN_CH];         // 1 KB
    int t = threadIdx.x;
    for (int i = t; i < IN_CH * HIDDEN; i += 256) {
        int k = i >> 6, c = i & 63;
        sWT[c * WT1_LD + k] = W[i];
    }

    int n0 = blockIdx.x * 16;
    int w = t >> 6;
    int lane = t & 63;
    int e16 = lane >> 2;          // edge slot 0..15
    int cc = (lane & 3) * 4;      // channel quad

    int lens[4], starts[4];
#pragma unroll
    for (int q = 0; q < 4; q++) {
        int n = n0 + w * 4 + q;
        lens[q] = cnt[n];
        starts[q] = rowptr[n];
    }

    for (int q = 0; q < 4; q++) {
        int row = w * 4 + q;
        int n = n0 + row;
        int len = lens[q];
        int start = starts[q];
        int last = len - 1;
        int iters = (len + 31) >> 5;   // wave-uniform, 32 edges per iter
        float4 acc = make_float4(0.f, 0.f, 0.f, 0.f);
        for (int m = 0; m < iters; m++) {
            int base = m * 32 + e16;
#pragma unroll
            for (int k = 0; k < 2; k++) {
                int j = base + 16 * k;
                int jj = j <= last ? j : last;
                float msk = j <= last ? 1.0f : 0.0f;
                int s = csr_src[start + jj];
                float4 xv = *(const float4*)&xs[s * IN_CH + cc];
                acc.x += msk * xv.x; acc.y += msk * xv.y;
                acc.z += msk * xv.z; acc.w += msk * xv.w;
            }
        }
#pragma unroll
        for (int m = 4; m <= 32; m <<= 1) {
            acc.x += __shfl_xor(acc.x, m, 64);
            acc.y += __shfl_xor(acc.y, m, 64);
            acc.z += __shfl_xor(acc.z, m, 64);
            acc.w += __shfl_xor(acc.w, m, 64);
        }
        if (lane < 4) {
            float dn = dinv[n];
            float4 xsv = *(const float4*)&xs[n * IN_CH + cc];
            float4 v;
            v.x = dn * (acc.x + xsv.x);
            v.y = dn * (acc.y + xsv.y);
            v.z = dn * (acc.z + xsv.z);
            v.w = dn * (acc.w + xsv.w);
            *(float4*)&sx[row * IN_CH + cc] = v;
        }
    }
    __syncthreads();

    int r = w;
    int c = t & 63;
    float bias = b[c];
#pragma unroll
    for (int nb = 0; nb < 4; nb++) {
        int row = nb * 4 + r;
        int n = n0 + row;
        if (n >= N_NODES) continue;
        float acch = bias;
#pragma unroll
        for (int k4 = 0; k4 < IN_CH; k4 += 4) {
            float4 a = *(const float4*)&sx[row * IN_CH + k4];
            float2 w0 = *(const float2*)&sWT[c * WT1_LD + k4];
            float2 w1 = *(const float2*)&sWT[c * WT1_LD + k4 + 2];
            acch += a.x * w0.x + a.y * w0.y + a.z * w1.x + a.w * w1.y;
        }
        float v = acch > 0.0f ? acch : 0.0f;
        h[n * HIDDEN + c] = __float2bfloat16(dinv[n] * v);   // pre-scaled h1'
    }
}

// ---------------- fused layer 2: aggregate(h1') -> MFMA gemm2 -> pool ----------------

__global__ void fused_l2_kernel(const __hip_bfloat16* __restrict__ h, const int* __restrict__ csr_src,
                                const int* __restrict__ rowptr, const int* __restrict__ cnt,
                                const float* __restrict__ dinv, const unsigned short* __restrict__ w2t,
                                const float* __restrict__ b, const int* __restrict__ batch,
                                float* __restrict__ sums, float* __restrict__ cntg) {
    __shared__ unsigned short sW[W2T_ENT];           // 9.2 KB (prepped, flat copy)
    __shared__ unsigned short sagg[16 * AGG_LD];     // 2.3 KB
    int t = threadIdx.x;
    {   // flat uint4 copy of prepped W2^T (conflict-free b128)
        const uint4* wp = (const uint4*)w2t;
        uint4* sWv = (uint4*)sW;
#pragma unroll
        for (int i = 0; i < 3; i++) {
            int idx = i * 256 + t;
            if (idx < W2T_ENT / 8) sWv[idx] = wp[idx];
        }
    }

    int n0 = blockIdx.x * 16;
    int w = t >> 6;
    int lane = t & 63;
    int e8 = lane >> 3;          // edge slot 0..7
    int cc8 = (lane & 7) * 8;    // channel octet
    const unsigned short* hu = (const unsigned short*)h;

    int lens[4], starts[4];
#pragma unroll
    for (int q = 0; q < 4; q++) {
        int n = n0 + w * 4 + q;
        lens[q] = cnt[n];
        starts[q] = rowptr[n];
    }

    for (int q = 0; q < 4; q++) {
        int row = w * 4 + q;
        int n = n0 + row;
        int len = lens[q];
        int start = starts[q];
        int last = len - 1;
        int iters = (len + 31) >> 5;   // 32 edges per iter
        float4 alo = make_float4(0.f, 0.f, 0.f, 0.f);
        float4 ahi = make_float4(0.f, 0.f, 0.f, 0.f);
        for (int m = 0; m < iters; m++) {
            int base = m * 32 + e8;
#pragma unroll
            for (int k = 0; k < 4; k++) {
                int j = base + 8 * k;
                int jj = j <= last ? j : last;
                float msk = j <= last ? 1.0f : 0.0f;
                int s = csr_src[start + jj];
                uint4 raw = *(const uint4*)&hu[s * HIDDEN + cc8];
                alo.x += msk * __uint_as_float(raw.x << 16);
                alo.y += msk * __uint_as_float(raw.x & 0xffff0000u);
                alo.z += msk * __uint_as_float(raw.y << 16);
                alo.w += msk * __uint_as_float(raw.y & 0xffff0000u);
                ahi.x += msk * __uint_as_float(raw.z << 16);
                ahi.y += msk * __uint_as_float(raw.z & 0xffff0000u);
                ahi.z += msk * __uint_as_float(raw.w << 16);
                ahi.w += msk * __uint_as_float(raw.w & 0xffff0000u);
            }
        }
#pragma unroll
        for (int m = 8; m <= 32; m <<= 1) {
            alo.x += __shfl_xor(alo.x, m, 64);
            alo.y += __shfl_xor(alo.y, m, 64);
            alo.z += __shfl_xor(alo.z, m, 64);
            alo.w += __shfl_xor(alo.w, m, 64);
            ahi.x += __shfl_xor(ahi.x, m, 64);
            ahi.y += __shfl_xor(ahi.y, m, 64);
            ahi.z += __shfl_xor(ahi.z, m, 64);
            ahi.w += __shfl_xor(ahi.w, m, 64);
        }
        if (lane < 8) {
            uint4 sv = *(const uint4*)&hu[n * HIDDEN + cc8];
            float dn = dinv[n];
            ushort4 o0, o1;
            o0.x = f2bf(dn * (alo.x + __uint_as_float(sv.x << 16)));
            o0.y = f2bf(dn * (alo.y + __uint_as_float(sv.x & 0xffff0000u)));
            o0.z = f2bf(dn * (alo.z + __uint_as_float(sv.y << 16)));
            o0.w = f2bf(dn * (alo.w + __uint_as_float(sv.y & 0xffff0000u)));
            o1.x = f2bf(dn * (ahi.x + __uint_as_float(sv.z << 16)));
            o1.y = f2bf(dn * (ahi.y + __uint_as_float(sv.z & 0xffff0000u)));
            o1.z = f2bf(dn * (ahi.z + __uint_as_float(sv.w << 16)));
            o1.w = f2bf(dn * (ahi.w + __uint_as_float(sv.w & 0xffff0000u)));
            *(ushort4*)&sagg[row * AGG_LD + cc8] = o0;
            *(ushort4*)&sagg[row * AGG_LD + cc8 + 4] = o1;
        }
    }
    __syncthreads();

    // Phase B: MFMA. Wave w computes all 16 nodes x channels [16w, 16w+16).
    int quad = lane >> 4;
    int col = lane & 15;
    int cch = w * 16 + col;
    bf16x8 a0 = *(const bf16x8*)&sagg[col * AGG_LD + quad * 8];
    bf16x8 a1 = *(const bf16x8*)&sagg[col * AGG_LD + 32 + quad * 8];
    bf16x8 b0 = *(const bf16x8*)&sW[cch * AGG_LD + quad * 8];
    bf16x8 b1 = *(const bf16x8*)&sW[cch * AGG_LD + 32 + quad * 8];
    f32x4 d = {0.f, 0.f, 0.f, 0.f};
    d = __builtin_amdgcn_mfma_f32_16x16x32_bf16(a0, b0, d, 0, 0, 0);
    d = __builtin_amdgcn_mfma_f32_16x16x32_bf16(a1, b1, d, 0, 0, 0);
    float bias = b[cch];
    float v[4];
#pragma unroll
    for (int r = 0; r < 4; r++) {
        float z = d[r] + bias;
        v[r] = z > 0.0f ? z : 0.0f;
    }

    // Phase C: pool from registers (batch sorted -> tile usually one graph)
    int glo = batch[n0];
    int ghi = batch[n0 + 15];
    if (glo == ghi) {
        float s4 = (v[0] + v[1]) + (v[2] + v[3]);
        s4 += __shfl_xor(s4, 16, 64);
        s4 += __shfl_xor(s4, 32, 64);
        if (quad == 0) atomicAdd(&sums[glo * HIDDEN + cch], s4);
        if (t == 0) atomicAdd(&cntg[glo], 16.0f);
    } else {
#pragma unroll
        for (int r = 0; r < 4; r++) {
            int g = batch[n0 + quad * 4 + r];
            if ((unsigned)g < N_GRAPHS) atomicAdd(&sums[g * HIDDEN + cch], v[r]);
        }
        if (w == 0 && col == 0) {
#pragma unroll
            for (int r = 0; r < 4; r++) {
                int g = batch[n0 + quad * 4 + r];
                if ((unsigned)g < N_GRAPHS) atomicAdd(&cntg[g], 1.0f);
            }
        }
    }
}

// ---------------- head ----------------

__global__ void head_kernel(const float* __restrict__ sums, const float* __restrict__ cntg,
                            const float* __restrict__ Wc, const float* __restrict__ bc,
                            float* __restrict__ out) {
    int t = blockIdx.x * blockDim.x + threadIdx.x;
    if (t >= N_GRAPHS * OUT_CH) return;
    int g = t >> 1;
    int o = t & 1;
    float inv = 1.0f / fmaxf(cntg[g], 1.0f);
    float acc = bc[o];
#pragma unroll
    for (int k = 0; k < HIDDEN; k++) acc += sums[g * HIDDEN + k] * inv * Wc[k * OUT_CH + o];
    out[t] = acc;
}

// ---------------- launch ----------------

extern "C" void kernel_launch(void* const* d_in, const int* in_sizes, int n_in,
                              void* d_out, int out_size, void* d_ws, size_t ws_size,
                              hipStream_t stream) {
    const float* x  = (const float*)d_in[0];
    const int* ei   = (const int*)d_in[1];
    const int* bat  = (const int*)d_in[2];
    const float* W1 = (const float*)d_in[3];
    const float* b1 = (const float*)d_in[4];
    const float* W2 = (const float*)d_in[5];
    const float* b2 = (const float*)d_in[6];
    const float* Wc = (const float*)d_in[7];
    const float* bc = (const float*)d_in[8];
    float* out = (float*)d_out;

    const int* src = ei;
    const int* dst = ei + N_EDGES;

    char* ws = (char*)d_ws;
    size_t off = 0;
    auto carve = [&](size_t nbytes) {
        char* p = ws + off;
        off += (nbytes + 255) & ~(size_t)255;
        return p;
    };
    float* sums     = (float*)carve(N_GRAPHS * HIDDEN * sizeof(float));
    float* cntg     = (float*)carve(N_GRAPHS * sizeof(float));
    unsigned short* w2t = (unsigned short*)carve(W2T_ENT * sizeof(unsigned short));
    int*   bh       = (int*)carve((size_t)NB * EB * sizeof(int));
    int*   bh2      = (int*)carve((size_t)NB * EB * sizeof(int));
    int*   pairs    = (int*)carve((size_t)EB * ECHUNK * sizeof(int));
    int*   csr      = (int*)carve((size_t)NB * BCAP * sizeof(int));
    int*   rowptr   = (int*)carve(N_NODES * sizeof(int));
    int*   cnt_node = (int*)carve(N_NODES * sizeof(int));
    float* dinv     = (float*)carve(N_NODES * sizeof(float));
    float* xs       = (float*)carve((size_t)N_NODES * IN_CH * sizeof(float));
    __hip_bfloat16* bufA = (__hip_bfloat16*)carve((size_t)N_NODES * HIDDEN * sizeof(__hip_bfloat16));
    (void)ws_size;

    const int node16Blk = (N_NODES + 15) / 16;   // 3125

    bucket_scatter_kernel<<<EB, 256, 0, stream>>>(src, dst, bh, bh2, pairs, W2, w2t);
    bucket_csr_kernel<<<NB, 256, 0, stream>>>(pairs, bh, bh2, csr, rowptr, cnt_node, dinv,
                                              x, xs, sums, cntg);
    fused_l1_kernel<<<node16Blk, 256, 0, stream>>>(xs, csr, rowptr, cnt_node, dinv, W1, b1, bufA);
    fused_l2_kernel<<<node16Blk, 256, 0, stream>>>(bufA, csr, rowptr, cnt_node, dinv, w2t, b2,
                                                   bat, sums, cntg);
    head_kernel<<<1, 256, 0, stream>>>(sums, cntg, Wc, bc, out);
}

// Round 15
// 164.592 us; speedup vs baseline: 2.3640x; 1.0087x over previous
//
#include <hip/hip_runtime.h>
#include <hip/hip_bf16.h>

#define N_NODES 50000
#define N_EDGES 800000
#define N_GRAPHS 128
#define IN_CH 16
#define HIDDEN 64
#define OUT_CH 2

// ---- bucket CSR params ----
#define BSHIFT 7
#define BNODES 128
#define NB ((N_NODES + BNODES - 1) / BNODES)     // 391 buckets
#define BCAP 3072                                // per-bucket csr capacity (mean 2046, sd ~45)
#define ECHUNK 4096
#define EB ((N_EDGES + ECHUNK - 1) / ECHUNK)     // 196 edge blocks
#define MAXK 12                                  // BCAP/256
#define EPT 16                                   // edges per thread in scatter (4096/256)
#define WT1_LD 18                                // W1^T stride: 2-way banks (free)
#define AGG_LD 72                                // bf16 LDS stride for MFMA frags
#define W2T_ENT (HIDDEN * AGG_LD)                // 4608 ushorts prepped W2^T

typedef __attribute__((ext_vector_type(8))) short bf16x8;
typedef __attribute__((ext_vector_type(4))) float f32x4;

__device__ __forceinline__ float bf2f(unsigned short u) {
    return __uint_as_float(((unsigned)u) << 16);
}
__device__ __forceinline__ unsigned short f2bf(float f) {
    __hip_bfloat16 h = __float2bfloat16(f);
    return *reinterpret_cast<unsigned short*>(&h);
}

// ---------------- S1: in-block bucket sort (zero global atomics, no init needed) ----------------

__global__ void bucket_scatter_kernel(const int* __restrict__ src, const int* __restrict__ dst,
                                      int* __restrict__ bh, int* __restrict__ bh2,
                                      int* __restrict__ pairs,
                                      const float* __restrict__ W2, unsigned short* __restrict__ w2t) {
    __shared__ int lh[NB];      // counts, then reused as cursors
    __shared__ int lstart[NB];  // exclusive prefix within block
    __shared__ int spair[256];  // scan temp
    int t = threadIdx.x;
    if (blockIdx.x == 0) {
        for (int i = t; i < HIDDEN * HIDDEN; i += 256) {
            int k = i >> 6, c = i & 63;
            w2t[c * AGG_LD + k] = f2bf(W2[i]);
        }
    }
    for (int i = t; i < NB; i += 256) lh[i] = 0;
    __syncthreads();

    int base = blockIdx.x * ECHUNK;
    int nE = N_EDGES - base;
    if (nE > ECHUNK) nE = ECHUNK;

    int ed[EPT], es[EPT];
#pragma unroll
    for (int k = 0; k < EPT; k++) {
        int i = k * 256 + t;
        if (i < nE) {
            ed[k] = dst[base + i];
            es[k] = src[base + i];
        } else {
            ed[k] = -1;
            es[k] = 0;
        }
    }
#pragma unroll
    for (int k = 0; k < EPT; k++)
        if ((unsigned)ed[k] < N_NODES) atomicAdd(&lh[ed[k] >> BSHIFT], 1);
    __syncthreads();

    // exclusive prefix over lh[0..NB): 2 entries/thread + 256-wide Hillis-Steele
    int a0 = (2 * t < NB) ? lh[2 * t] : 0;
    int a1 = (2 * t + 1 < NB) ? lh[2 * t + 1] : 0;
    spair[t] = a0 + a1;
    __syncthreads();
    for (int off = 1; off < 256; off <<= 1) {
        int u = (t >= off) ? spair[t - off] : 0;
        __syncthreads();
        spair[t] += u;
        __syncthreads();
    }
    int ex = spair[t] - (a0 + a1);
    if (2 * t < NB) lstart[2 * t] = ex;
    if (2 * t + 1 < NB) lstart[2 * t + 1] = ex + a0;
    __syncthreads();

    // publish tables, reset cursors
    for (int i = t; i < NB; i += 256) {
        bh[i * EB + blockIdx.x] = lh[i];
        bh2[i * EB + blockIdx.x] = base + lstart[i];
        lh[i] = 0;
    }
    __syncthreads();

#pragma unroll
    for (int k = 0; k < EPT; k++) {
        if ((unsigned)ed[k] < N_NODES) {
            int b = ed[k] >> BSHIFT;
            int r = atomicAdd(&lh[b], 1);
            pairs[base + lstart[b] + r] = (es[k] << BSHIFT) | (ed[k] & (BNODES - 1));
        }
    }
}

// ---------------- S2: per-bucket exact CSR (+dinv, +x' bf16, + zero sums/cntg) ----------------

__global__ void bucket_csr_kernel(const int* __restrict__ pairs, const int* __restrict__ bh,
                                  const int* __restrict__ bh2,
                                  int* __restrict__ csr, int* __restrict__ rowptr,
                                  int* __restrict__ cnt_node, float* __restrict__ dinv,
                                  const float* __restrict__ x, unsigned short* __restrict__ xs,
                                  float* __restrict__ sums, float* __restrict__ cntg) {
    __shared__ int segaddr[EB];
    __shared__ int pref[EB];       // inclusive prefix of segment counts
    __shared__ int ptmp[256];
    __shared__ int lcnt[BNODES];
    __shared__ int lsc[BNODES];
    __shared__ int lrow[BNODES];
    __shared__ float sdv[BNODES];
    int b = blockIdx.x;
    int t = threadIdx.x;

    if (b == 0) {   // zero everything the later kernels accumulate into
        for (int i = t; i < N_GRAPHS * HIDDEN; i += 256) sums[i] = 0.0f;
        if (t < N_GRAPHS) cntg[t] = 0.0f;
    }

    int cntv = (t < EB) ? bh[b * EB + t] : 0;
    if (t < EB) segaddr[t] = bh2[b * EB + t];
    if (t < BNODES) lcnt[t] = 0;
    ptmp[t] = cntv;
    __syncthreads();
    for (int off = 1; off < 256; off <<= 1) {
        int u = (t >= off) ? ptmp[t - off] : 0;
        __syncthreads();
        ptmp[t] += u;
        __syncthreads();
    }
    if (t < EB) pref[t] = ptmp[t];
    __syncthreads();
    int K = pref[EB - 1];
    if (K > BCAP) K = BCAP;   // safety cap (matches csr region capacity)

    int myp[MAXK], myr[MAXK];
#pragma unroll
    for (int k = 0; k < MAXK; k++) {
        int i = k * 256 + t;
        myp[k] = -1;
        if (i < K) {
            int lo = 0, hi = EB - 1;          // smallest seg with pref[seg] > i
            while (lo < hi) {
                int mid = (lo + hi) >> 1;
                if (pref[mid] > i) hi = mid; else lo = mid + 1;
            }
            int excl = (lo > 0) ? pref[lo - 1] : 0;
            int p = pairs[segaddr[lo] + (i - excl)];
            myp[k] = p;
            myr[k] = atomicAdd(&lcnt[p & (BNODES - 1)], 1);
        }
    }
    __syncthreads();
    if (t < BNODES) lsc[t] = lcnt[t];
    __syncthreads();
    for (int off = 1; off < BNODES; off <<= 1) {
        int u = (t >= off && t < BNODES) ? lsc[t - off] : 0;
        __syncthreads();
        if (t < BNODES) lsc[t] += u;
        __syncthreads();
    }
    int bstart = b * BCAP;
    if (t < BNODES) {
        int ex = lsc[t] - lcnt[t];
        lrow[t] = ex;
        float dv = rsqrtf((float)(lcnt[t] + 1));  // +1 self-loop
        sdv[t] = dv;
        int n = b * BNODES + t;
        if (n < N_NODES) {
            rowptr[n] = bstart + ex;
            cnt_node[n] = lcnt[t];
            dinv[n] = dv;
        }
    }
    __syncthreads();
#pragma unroll
    for (int k = 0; k < MAXK; k++) {
        if (myp[k] >= 0)
            csr[bstart + lrow[myp[k] & (BNODES - 1)] + myr[k]] = myp[k] >> BSHIFT;
    }
    // prep x' = dinv * x (bf16) for this bucket's 128 nodes
    for (int i = t; i < BNODES * IN_CH; i += 256) {
        int nl = i >> 4;
        int n = b * BNODES + nl;
        if (n < N_NODES) xs[n * IN_CH + (i & 15)] = f2bf(sdv[nl] * x[n * IN_CH + (i & 15)]);
    }
}

// ---------------- fused layer 1: aggregate(x' bf16) -> LDS -> linear+relu -> h1' (bf16) ----------------

// Phase A: 4 lanes/edge, ushort4 (8 B) per lane; wave-uniform iters, 2 masked slots.
__global__ void fused_l1_kernel(const unsigned short* __restrict__ xs, const int* __restrict__ csr_src,
                                const int* __restrict__ rowptr, const int* __restrict__ cnt,
                                const float* __restrict__ dinv, const float* __restrict__ W,
                                const float* __restrict__ b, __hip_bfloat16* __restrict__ h) {
    __shared__ float sWT[HIDDEN * WT1_LD];   // 4.6 KB
    __shared__ float sx[16 * IN_CH];         // 1 KB
    int t = threadIdx.x;
    for (int i = t; i < IN_CH * HIDDEN; i += 256) {
        int k = i >> 6, c = i & 63;
        sWT[c * WT1_LD + k] = W[i];
    }

    int n0 = blockIdx.x * 16;
    int w = t >> 6;
    int lane = t & 63;
    int e16 = lane >> 2;          // edge slot 0..15
    int cc = (lane & 3) * 4;      // channel quad

    int lens[4], starts[4];
#pragma unroll
    for (int q = 0; q < 4; q++) {
        int n = n0 + w * 4 + q;
        lens[q] = cnt[n];
        starts[q] = rowptr[n];
    }

    for (int q = 0; q < 4; q++) {
        int row = w * 4 + q;
        int n = n0 + row;
        int len = lens[q];
        int start = starts[q];
        int last = len - 1;
        int iters = (len + 31) >> 5;   // wave-uniform, 32 edges per iter
        float4 acc = make_float4(0.f, 0.f, 0.f, 0.f);
        for (int m = 0; m < iters; m++) {
            int base = m * 32 + e16;
#pragma unroll
            for (int k = 0; k < 2; k++) {
                int j = base + 16 * k;
                int jj = j <= last ? j : last;
                float msk = j <= last ? 1.0f : 0.0f;
                int s = csr_src[start + jj];
                ushort4 xv = *(const ushort4*)&xs[s * IN_CH + cc];
                acc.x += msk * bf2f(xv.x);
                acc.y += msk * bf2f(xv.y);
                acc.z += msk * bf2f(xv.z);
                acc.w += msk * bf2f(xv.w);
            }
        }
#pragma unroll
        for (int m = 4; m <= 32; m <<= 1) {
            acc.x += __shfl_xor(acc.x, m, 64);
            acc.y += __shfl_xor(acc.y, m, 64);
            acc.z += __shfl_xor(acc.z, m, 64);
            acc.w += __shfl_xor(acc.w, m, 64);
        }
        if (lane < 4) {
            float dn = dinv[n];
            ushort4 xsv = *(const ushort4*)&xs[n * IN_CH + cc];
            float4 v;
            v.x = dn * (acc.x + bf2f(xsv.x));
            v.y = dn * (acc.y + bf2f(xsv.y));
            v.z = dn * (acc.z + bf2f(xsv.z));
            v.w = dn * (acc.w + bf2f(xsv.w));
            *(float4*)&sx[row * IN_CH + cc] = v;
        }
    }
    __syncthreads();

    int r = w;
    int c = t & 63;
    float bias = b[c];
#pragma unroll
    for (int nb = 0; nb < 4; nb++) {
        int row = nb * 4 + r;
        int n = n0 + row;
        if (n >= N_NODES) continue;
        float acch = bias;
#pragma unroll
        for (int k4 = 0; k4 < IN_CH; k4 += 4) {
            float4 a = *(const float4*)&sx[row * IN_CH + k4];
            float2 w0 = *(const float2*)&sWT[c * WT1_LD + k4];
            float2 w1 = *(const float2*)&sWT[c * WT1_LD + k4 + 2];
            acch += a.x * w0.x + a.y * w0.y + a.z * w1.x + a.w * w1.y;
        }
        float v = acch > 0.0f ? acch : 0.0f;
        h[n * HIDDEN + c] = __float2bfloat16(dinv[n] * v);   // pre-scaled h1'
    }
}

// ---------------- fused layer 2: aggregate(h1') -> MFMA gemm2 -> pool ----------------

__global__ void fused_l2_kernel(const __hip_bfloat16* __restrict__ h, const int* __restrict__ csr_src,
                                const int* __restrict__ rowptr, const int* __restrict__ cnt,
                                const float* __restrict__ dinv, const unsigned short* __restrict__ w2t,
                                const float* __restrict__ b, const int* __restrict__ batch,
                                float* __restrict__ sums, float* __restrict__ cntg) {
    __shared__ unsigned short sW[W2T_ENT];           // 9.2 KB (prepped, flat copy)
    __shared__ unsigned short sagg[16 * AGG_LD];     // 2.3 KB
    int t = threadIdx.x;
    {   // flat uint4 copy of prepped W2^T (conflict-free b128)
        const uint4* wp = (const uint4*)w2t;
        uint4* sWv = (uint4*)sW;
#pragma unroll
        for (int i = 0; i < 3; i++) {
            int idx = i * 256 + t;
            if (idx < W2T_ENT / 8) sWv[idx] = wp[idx];
        }
    }

    int n0 = blockIdx.x * 16;
    int w = t >> 6;
    int lane = t & 63;
    int e8 = lane >> 3;          // edge slot 0..7
    int cc8 = (lane & 7) * 8;    // channel octet
    const unsigned short* hu = (const unsigned short*)h;

    int lens[4], starts[4];
#pragma unroll
    for (int q = 0; q < 4; q++) {
        int n = n0 + w * 4 + q;
        lens[q] = cnt[n];
        starts[q] = rowptr[n];
    }

    for (int q = 0; q < 4; q++) {
        int row = w * 4 + q;
        int n = n0 + row;
        int len = lens[q];
        int start = starts[q];
        int last = len - 1;
        int iters = (len + 31) >> 5;   // 32 edges per iter
        float4 alo = make_float4(0.f, 0.f, 0.f, 0.f);
        float4 ahi = make_float4(0.f, 0.f, 0.f, 0.f);
        for (int m = 0; m < iters; m++) {
            int base = m * 32 + e8;
#pragma unroll
            for (int k = 0; k < 4; k++) {
                int j = base + 8 * k;
                int jj = j <= last ? j : last;
                float msk = j <= last ? 1.0f : 0.0f;
                int s = csr_src[start + jj];
                uint4 raw = *(const uint4*)&hu[s * HIDDEN + cc8];
                alo.x += msk * __uint_as_float(raw.x << 16);
                alo.y += msk * __uint_as_float(raw.x & 0xffff0000u);
                alo.z += msk * __uint_as_float(raw.y << 16);
                alo.w += msk * __uint_as_float(raw.y & 0xffff0000u);
                ahi.x += msk * __uint_as_float(raw.z << 16);
                ahi.y += msk * __uint_as_float(raw.z & 0xffff0000u);
                ahi.z += msk * __uint_as_float(raw.w << 16);
                ahi.w += msk * __uint_as_float(raw.w & 0xffff0000u);
            }
        }
#pragma unroll
        for (int m = 8; m <= 32; m <<= 1) {
            alo.x += __shfl_xor(alo.x, m, 64);
            alo.y += __shfl_xor(alo.y, m, 64);
            alo.z += __shfl_xor(alo.z, m, 64);
            alo.w += __shfl_xor(alo.w, m, 64);
            ahi.x += __shfl_xor(ahi.x, m, 64);
            ahi.y += __shfl_xor(ahi.y, m, 64);
            ahi.z += __shfl_xor(ahi.z, m, 64);
            ahi.w += __shfl_xor(ahi.w, m, 64);
        }
        if (lane < 8) {
            uint4 sv = *(const uint4*)&hu[n * HIDDEN + cc8];
            float dn = dinv[n];
            ushort4 o0, o1;
            o0.x = f2bf(dn * (alo.x + __uint_as_float(sv.x << 16)));
            o0.y = f2bf(dn * (alo.y + __uint_as_float(sv.x & 0xffff0000u)));
            o0.z = f2bf(dn * (alo.z + __uint_as_float(sv.y << 16)));
            o0.w = f2bf(dn * (alo.w + __uint_as_float(sv.y & 0xffff0000u)));
            o1.x = f2bf(dn * (ahi.x + __uint_as_float(sv.z << 16)));
            o1.y = f2bf(dn * (ahi.y + __uint_as_float(sv.z & 0xffff0000u)));
            o1.z = f2bf(dn * (ahi.z + __uint_as_float(sv.w << 16)));
            o1.w = f2bf(dn * (ahi.w + __uint_as_float(sv.w & 0xffff0000u)));
            *(ushort4*)&sagg[row * AGG_LD + cc8] = o0;
            *(ushort4*)&sagg[row * AGG_LD + cc8 + 4] = o1;
        }
    }
    __syncthreads();

    // Phase B: MFMA. Wave w computes all 16 nodes x channels [16w, 16w+16).
    int quad = lane >> 4;
    int col = lane & 15;
    int cch = w * 16 + col;
    bf16x8 a0 = *(const bf16x8*)&sagg[col * AGG_LD + quad * 8];
    bf16x8 a1 = *(const bf16x8*)&sagg[col * AGG_LD + 32 + quad * 8];
    bf16x8 b0 = *(const bf16x8*)&sW[cch * AGG_LD + quad * 8];
    bf16x8 b1 = *(const bf16x8*)&sW[cch * AGG_LD + 32 + quad * 8];
    f32x4 d = {0.f, 0.f, 0.f, 0.f};
    d = __builtin_amdgcn_mfma_f32_16x16x32_bf16(a0, b0, d, 0, 0, 0);
    d = __builtin_amdgcn_mfma_f32_16x16x32_bf16(a1, b1, d, 0, 0, 0);
    float bias = b[cch];
    float v[4];
#pragma unroll
    for (int r = 0; r < 4; r++) {
        float z = d[r] + bias;
        v[r] = z > 0.0f ? z : 0.0f;
    }

    // Phase C: pool from registers (batch sorted -> tile usually one graph)
    int glo = batch[n0];
    int ghi = batch[n0 + 15];
    if (glo == ghi) {
        float s4 = (v[0] + v[1]) + (v[2] + v[3]);
        s4 += __shfl_xor(s4, 16, 64);
        s4 += __shfl_xor(s4, 32, 64);
        if (quad == 0) atomicAdd(&sums[glo * HIDDEN + cch], s4);
        if (t == 0) atomicAdd(&cntg[glo], 16.0f);
    } else {
#pragma unroll
        for (int r = 0; r < 4; r++) {
            int g = batch[n0 + quad * 4 + r];
            if ((unsigned)g < N_GRAPHS) atomicAdd(&sums[g * HIDDEN + cch], v[r]);
        }
        if (w == 0 && col == 0) {
#pragma unroll
            for (int r = 0; r < 4; r++) {
                int g = batch[n0 + quad * 4 + r];
                if ((unsigned)g < N_GRAPHS) atomicAdd(&cntg[g], 1.0f);
            }
        }
    }
}

// ---------------- head ----------------

__global__ void head_kernel(const float* __restrict__ sums, const float* __restrict__ cntg,
                            const float* __restrict__ Wc, const float* __restrict__ bc,
                            float* __restrict__ out) {
    int t = blockIdx.x * blockDim.x + threadIdx.x;
    if (t >= N_GRAPHS * OUT_CH) return;
    int g = t >> 1;
    int o = t & 1;
    float inv = 1.0f / fmaxf(cntg[g], 1.0f);
    float acc = bc[o];
#pragma unroll
    for (int k = 0; k < HIDDEN; k++) acc += sums[g * HIDDEN + k] * inv * Wc[k * OUT_CH + o];
    out[t] = acc;
}

// ---------------- launch ----------------

extern "C" void kernel_launch(void* const* d_in, const int* in_sizes, int n_in,
                              void* d_out, int out_size, void* d_ws, size_t ws_size,
                              hipStream_t stream) {
    const float* x  = (const float*)d_in[0];
    const int* ei   = (const int*)d_in[1];
    const int* bat  = (const int*)d_in[2];
    const float* W1 = (const float*)d_in[3];
    const float* b1 = (const float*)d_in[4];
    const float* W2 = (const float*)d_in[5];
    const float* b2 = (const float*)d_in[6];
    const float* Wc = (const float*)d_in[7];
    const float* bc = (const float*)d_in[8];
    float* out = (float*)d_out;

    const int* src = ei;
    const int* dst = ei + N_EDGES;

    char* ws = (char*)d_ws;
    size_t off = 0;
    auto carve = [&](size_t nbytes) {
        char* p = ws + off;
        off += (nbytes + 255) & ~(size_t)255;
        return p;
    };
    float* sums     = (float*)carve(N_GRAPHS * HIDDEN * sizeof(float));
    float* cntg     = (float*)carve(N_GRAPHS * sizeof(float));
    unsigned short* w2t = (unsigned short*)carve(W2T_ENT * sizeof(unsigned short));
    int*   bh       = (int*)carve((size_t)NB * EB * sizeof(int));
    int*   bh2      = (int*)carve((size_t)NB * EB * sizeof(int));
    int*   pairs    = (int*)carve((size_t)EB * ECHUNK * sizeof(int));
    int*   csr      = (int*)carve((size_t)NB * BCAP * sizeof(int));
    int*   rowptr   = (int*)carve(N_NODES * sizeof(int));
    int*   cnt_node = (int*)carve(N_NODES * sizeof(int));
    float* dinv     = (float*)carve(N_NODES * sizeof(float));
    unsigned short* xs = (unsigned short*)carve((size_t)N_NODES * IN_CH * sizeof(unsigned short));
    __hip_bfloat16* bufA = (__hip_bfloat16*)carve((size_t)N_NODES * HIDDEN * sizeof(__hip_bfloat16));
    (void)ws_size;

    const int node16Blk = (N_NODES + 15) / 16;   // 3125

    bucket_scatter_kernel<<<EB, 256, 0, stream>>>(src, dst, bh, bh2, pairs, W2, w2t);
    bucket_csr_kernel<<<NB, 256, 0, stream>>>(pairs, bh, bh2, csr, rowptr, cnt_node, dinv,
                                              x, xs, sums, cntg);
    fused_l1_kernel<<<node16Blk, 256, 0, stream>>>(xs, csr, rowptr, cnt_node, dinv, W1, b1, bufA);
    fused_l2_kernel<<<node16Blk, 256, 0, stream>>>(bufA, csr, rowptr, cnt_node, dinv, w2t, b2,
                                                   bat, sums, cntg);
    head_kernel<<<1, 256, 0, stream>>>(sums, cntg, Wc, bc, out);
}